// Round 1
// baseline (272.792 us; speedup 1.0000x reference)
//
#include <hip/hip_runtime.h>
#include <math.h>

typedef unsigned short u16;
typedef unsigned int u32;
typedef __fp16 fp16x2 __attribute__((ext_vector_type(2)));
typedef _Float16 half8 __attribute__((ext_vector_type(8)));
typedef float f32x4 __attribute__((ext_vector_type(4)));

#define NH   12
#define SEQ  2048
#define CDIM 768

__device__ __forceinline__ u16 f2h(float f) {
  _Float16 h = (_Float16)f;
  return __builtin_bit_cast(u16, h);
}
__device__ __forceinline__ u32 pk2(float a, float b) {
  fp16x2 h = __builtin_amdgcn_cvt_pkrtz(a, b);    // v_cvt_pk_rtz_f16_f32
  return __builtin_bit_cast(u32, h);
}
// async global->LDS DMA, 16B per lane; LDS dest = wave-uniform base + lane*16
__device__ __forceinline__ void dma16(const u16* g, u16* l) {
  __builtin_amdgcn_global_load_lds(
      (const __attribute__((address_space(1))) u32*)g,
      (__attribute__((address_space(3))) u32*)l, 16, 0, 0);
}

// ---------------- fp32 -> f16 convert (optional scale) ----------------
__global__ __launch_bounds__(256) void cvt_f32_f16(const float* __restrict__ in,
                                                   u16* __restrict__ out, int n) {
  int i = (blockIdx.x * 256 + threadIdx.x) * 4;
  if (i < n) {
    float4 f = *(const float4*)(in + i);
    *(uint2*)(out + i) = make_uint2(pk2(f.x, f.y), pk2(f.z, f.w));
  }
}
__global__ __launch_bounds__(256) void cvt_f32_f16_scale(const float* __restrict__ in,
                                                         u16* __restrict__ out,
                                                         const float* __restrict__ taup, int n) {
  float t = *taup;
  float sp = (t > 20.f) ? t : log1pf(expf(t));
  float s = (0.125f / (sp + 1e-6f)) * 1.44269504088896340736f;  // qkscale * log2(e)
  int i = (blockIdx.x * 256 + threadIdx.x) * 4;
  if (i < n) {
    float4 f = *(const float4*)(in + i);
    *(uint2*)(out + i) = make_uint2(pk2(f.x * s, f.y * s), pk2(f.z * s, f.w * s));
  }
}

// ---------------- NT GEMM: C[M,N] = A[M,K] @ B[N,K]^T, f16 MFMA, fp32 acc ---
// Tile 64(M) x 128(N), BK=64, 2 waves each 64x64 (32 MFMA / 16 LDS reads per
// wave-iter). Staging via global_load_lds into unpadded 128B rows with
// chunk-XOR swizzle (source-permuted; read side XORs with l16&7) -> 2-way banks.
// NEW: 2-phase double-buffered staging — issue tile t+1's DMA before computing
// tile t; single __syncthreads per K-step (its vmcnt(0) drain lands after the
// compute, hiding the global->LDS latency that the old 2-barrier loop exposed).
// MODE 0: out0 = q [B,H,N,D] f16 (scale pre-folded into Wq)
// MODE 1: cols [0,768)->k [B,H,N,D]; [768,1536)->v transposed [B,H,D,N]
// MODE 2: fp32 out[M,N] = acc + bias[n]
template<int MODE>
__global__ __launch_bounds__(128, 3) void gemm_nt(
    const u16* __restrict__ A, const u16* __restrict__ B,
    u16* __restrict__ out0, u16* __restrict__ out1,
    float* __restrict__ outf, const float* __restrict__ bias,
    int M, int N, int K)
{
  __shared__ __align__(16) u16 As[2][64 * 64];    // [buf][m][k], swizzled, 2x8 KB
  __shared__ __align__(16) u16 Bs[2][128 * 64];   // [buf][n][k], swizzled, 2x16 KB
  const int tid = threadIdx.x;
  const int wave = tid >> 6, lane = tid & 63;
  const int quad = lane >> 4, l16 = lane & 15;
  const int row0 = blockIdx.x * 64, col0 = blockIdx.y * 128;

  const int sub = lane >> 3;                   // row within an 8-row DMA slab
  const int csw = ((lane & 7) ^ sub) * 8;      // swizzled source chunk (elems)

  f32x4 acc[4][4] = {};

  auto stage = [&](int k0, int bsel) {
    u16* Asp = As[bsel];
    u16* Bsp = Bs[bsel];
    #pragma unroll
    for (int i = 0; i < 4; i++) {
      int ii = wave * 4 + i;                   // A slabs 0..7 (8 rows each)
      dma16(A + (size_t)(row0 + ii * 8 + sub) * K + k0 + csw, Asp + ii * 512);
    }
    #pragma unroll
    for (int i = 0; i < 8; i++) {
      int ii = wave * 8 + i;                   // B slabs 0..15
      dma16(B + (size_t)(col0 + ii * 8 + sub) * K + k0 + csw, Bsp + ii * 512);
    }
  };

  stage(0, 0);
  __syncthreads();                             // drain tile-0 DMA

  const int nk = K >> 6;
  for (int t = 0; t < nk; t++) {
    const int cur = t & 1;
    if (t + 1 < nk) stage((t + 1) << 6, cur ^ 1);   // prefetch next tile
    const u16* Asp = As[cur];
    const u16* Bsp = Bs[cur];
    #pragma unroll
    for (int ks = 0; ks < 2; ks++) {
      half8 af[4], bfr[4];
      #pragma unroll
      for (int mt = 0; mt < 4; mt++)
        af[mt] = *(const half8*)&Asp[(mt * 16 + l16) * 64 + (((ks * 4 + quad) ^ (l16 & 7)) * 8)];
      #pragma unroll
      for (int nt = 0; nt < 4; nt++)
        bfr[nt] = *(const half8*)&Bsp[(wave * 64 + nt * 16 + l16) * 64 + (((ks * 4 + quad) ^ (l16 & 7)) * 8)];
      #pragma unroll
      for (int mt = 0; mt < 4; mt++)
        #pragma unroll
        for (int nt = 0; nt < 4; nt++)
          acc[mt][nt] = __builtin_amdgcn_mfma_f32_16x16x32_f16(af[mt], bfr[nt], acc[mt][nt], 0, 0, 0);
    }
    __syncthreads();   // readers done with buf[cur]; prefetch DMA drained (vmcnt 0)
  }

  // epilogue: C layout col=lane&15, row=quad*4+reg
  #pragma unroll
  for (int mt = 0; mt < 4; mt++)
  #pragma unroll
  for (int nt = 0; nt < 4; nt++)
  #pragma unroll
  for (int r = 0; r < 4; r++) {
    int gm = row0 + mt * 16 + quad * 4 + r;
    int gn = col0 + wave * 64 + nt * 16 + l16;
    float v = acc[mt][nt][r];
    if (MODE == 0) {
      int b = gm >> 11, n = gm & 2047;
      int h = gn >> 6, d = gn & 63;
      out0[(((size_t)(b * NH + h)) * SEQ + n) * 64 + d] = f2h(v);
    } else if (MODE == 1) {
      int b = gm >> 11, n = gm & 2047;
      if (gn < CDIM) {
        int h = gn >> 6, d = gn & 63;
        out0[(((size_t)(b * NH + h)) * SEQ + n) * 64 + d] = f2h(v);
      } else {
        int c = gn - CDIM;
        int h = c >> 6, d = c & 63;
        out1[(((size_t)(b * NH + h)) * 64 + d) * SEQ + n] = f2h(v);   // V^T: [B,H,D,N]
      }
    } else {
      outf[(size_t)gm * N + gn] = v + bias[gn];
    }
  }
}

// ---------------- flash attention (transposed-S, f16, no-max softmax) ------
// grid 48*(16 q-tiles of 128) = 768. 4 waves x 32 q-rows (mt=2). KV tile 64.
// K/V staged via global_load_lds into unpadded 128B rows, chunk-XOR swizzle.
// St = K Q^T so softmax rows live per-lane; fixed-shift softmax p=exp2(s).
// NEW: 2-phase double-buffered K/V staging (issue tile kt+1 before computing
// tile kt; one barrier per tile instead of two, DMA latency hidden under
// QK^T + softmax + PV compute).
__global__ __launch_bounds__(256, 3) void attn_kernel(
    const u16* __restrict__ Q, const u16* __restrict__ Kb,
    const u16* __restrict__ Vtg, u16* __restrict__ Ob)
{
  constexpr int LDP = 72;                      // Ps rows 144 B (16B-aligned)
  __shared__ __align__(16) u16 Ks[2][64 * 64];    // [buf][kk][d] swizzled, 2x8 KB
  __shared__ __align__(16) u16 Vs[2][64 * 64];    // [buf][d][kk] swizzled, 2x8 KB
  __shared__ __align__(16) u16 Ps[4 * 16 * LDP];

  const int qt = blockIdx.x & 15;
  const int bh = blockIdx.x >> 4;
  const int b = bh / NH, h = bh % NH;
  const u16* Qp = Q   + (size_t)bh * SEQ * 64;
  const u16* Kp = Kb  + (size_t)bh * SEQ * 64;
  const u16* Vp = Vtg + (size_t)bh * 64 * SEQ;

  const int tid = threadIdx.x;
  const int wave = tid >> 6, lane = tid & 63;
  const int quad = lane >> 4, l16 = lane & 15;
  const int sub = lane >> 3;
  const int csw = ((lane & 7) ^ sub) * 8;
  u16* Pw = Ps + wave * 16 * LDP;

  // Q fragments (B-operand): Q[m=l16][d=ks*32+quad*8+j], scale pre-folded
  half8 qf[2][2];
  #pragma unroll
  for (int mt = 0; mt < 2; mt++)
    #pragma unroll
    for (int ks = 0; ks < 2; ks++)
      qf[mt][ks] = *(const half8*)(Qp + (size_t)(qt * 128 + wave * 32 + mt * 16 + l16) * 64 + ks * 32 + quad * 8);

  f32x4 oacc[2][4] = {};
  float lrow[2] = {0.f, 0.f};

  auto stage = [&](int kt, int bsel) {
    #pragma unroll
    for (int i = 0; i < 2; i++) {
      int ii = wave * 2 + i;                   // slabs 0..7 (8 rows each)
      dma16(Kp + (size_t)(kt * 64 + ii * 8 + sub) * 64 + csw, &Ks[bsel][ii * 512]);
      dma16(Vp + (size_t)(ii * 8 + sub) * SEQ + kt * 64 + csw, &Vs[bsel][ii * 512]);
    }
  };

  stage(0, 0);
  __syncthreads();                             // drain tile-0 DMA

  for (int kt = 0; kt < SEQ / 64; kt++) {
    const int cur = kt & 1;
    if (kt + 1 < SEQ / 64) stage(kt + 1, cur ^ 1);   // prefetch next K/V tile
    const u16* Ksp = Ks[cur];
    const u16* Vsp = Vs[cur];

    // St = K Q^T : sacc[mt][ntk] holds St[kk=ntk*16+quad*4+r][m=l16]
    f32x4 sacc[2][4] = {};
    #pragma unroll
    for (int ks = 0; ks < 2; ks++) {
      #pragma unroll
      for (int ntk = 0; ntk < 4; ntk++) {
        half8 kf = *(const half8*)&Ksp[(ntk * 16 + l16) * 64 + (((ks * 4 + quad) ^ (l16 & 7)) * 8)];
        #pragma unroll
        for (int mt = 0; mt < 2; mt++)
          sacc[mt][ntk] = __builtin_amdgcn_mfma_f32_16x16x32_f16(kf, qf[mt][ks], sacc[mt][ntk], 0, 0, 0);
      }
    }

    // softmax (fixed shift): p = exp2(s); P -> LDS (C->A layout), per mt
    half8 pf[2][2];
    #pragma unroll
    for (int mt = 0; mt < 2; mt++) {
      #pragma unroll
      for (int ntk = 0; ntk < 4; ntk++) {
        float p0 = exp2f(sacc[mt][ntk][0]);
        float p1 = exp2f(sacc[mt][ntk][1]);
        float p2 = exp2f(sacc[mt][ntk][2]);
        float p3 = exp2f(sacc[mt][ntk][3]);
        lrow[mt] += (p0 + p1) + (p2 + p3);
        *(uint2*)(&Pw[l16 * LDP + ntk * 16 + quad * 4]) = make_uint2(pk2(p0, p1), pk2(p2, p3));
      }
      pf[mt][0] = *(const half8*)&Pw[l16 * LDP + quad * 8];
      pf[mt][1] = *(const half8*)&Pw[l16 * LDP + 32 + quad * 8];
    }

    // O += P V (vf reused across mt)
    #pragma unroll
    for (int ks = 0; ks < 2; ks++)
      #pragma unroll
      for (int dt = 0; dt < 4; dt++) {
        half8 vf = *(const half8*)&Vsp[(dt * 16 + l16) * 64 + (((ks * 4 + quad) ^ (l16 & 7)) * 8)];
        #pragma unroll
        for (int mt = 0; mt < 2; mt++)
          oacc[mt][dt] = __builtin_amdgcn_mfma_f32_16x16x32_f16(pf[mt][ks], vf, oacc[mt][dt], 0, 0, 0);
      }

    __syncthreads();   // readers done with buf[cur]; prefetch DMA drained
  }

  // reduce l across quads (per-lane partials for row l16)
  #pragma unroll
  for (int mt = 0; mt < 2; mt++) {
    lrow[mt] += __shfl_xor(lrow[mt], 16);
    lrow[mt] += __shfl_xor(lrow[mt], 32);
  }

  // epilogue: O / l -> ao[b][n][h*64+d] (f16)
  #pragma unroll
  for (int mt = 0; mt < 2; mt++) {
    float lv[4];
    #pragma unroll
    for (int r = 0; r < 4; r++) lv[r] = __shfl(lrow[mt], quad * 4 + r);
    #pragma unroll
    for (int r = 0; r < 4; r++) {
      float inv = 1.0f / lv[r];
      int n = qt * 128 + wave * 32 + mt * 16 + quad * 4 + r;
      size_t base = ((size_t)b * SEQ + n) * CDIM + h * 64;
      #pragma unroll
      for (int dt = 0; dt < 4; dt++)
        Ob[base + dt * 16 + l16] = f2h(oacc[mt][dt][r] * inv);
    }
  }
}

// ---------------- launch ----------------
extern "C" void kernel_launch(void* const* d_in, const int* in_sizes, int n_in,
                              void* d_out, int out_size, void* d_ws, size_t ws_size,
                              hipStream_t stream)
{
  const float* x     = (const float*)d_in[0];
  const float* y     = (const float*)d_in[1];
  const float* Wq    = (const float*)d_in[2];
  const float* Wkv   = (const float*)d_in[3];
  const float* taup  = (const float*)d_in[4];
  const float* Wproj = (const float*)d_in[5];
  const float* bproj = (const float*)d_in[6];
  float* out = (float*)d_out;

  char* ws = (char*)d_ws;
  size_t off = 0;
  auto alloc = [&](size_t bytes) { char* p = ws + off; off += bytes; return p; };
  u16* xh  = (u16*)alloc(8192ull * 768 * 2);
  u16* yh  = (u16*)alloc(8192ull * 768 * 2);
  u16* wqh = (u16*)alloc(768ull * 768 * 2);
  u16* wkh = (u16*)alloc(1536ull * 768 * 2);
  u16* wph = (u16*)alloc(768ull * 768 * 2);
  u16* qb  = (u16*)alloc(8192ull * 768 * 2);   // [B,H,N,D] f16, scale folded
  u16* kb  = (u16*)alloc(8192ull * 768 * 2);   // [B,H,N,D]
  u16* vtb = (u16*)alloc(8192ull * 768 * 2);   // [B,H,D,N]
  u16* ao  = (u16*)alloc(8192ull * 768 * 2);   // [B,N,C]

  cvt_f32_f16<<<6144, 256, 0, stream>>>(x, xh, 8192 * 768);
  cvt_f32_f16<<<6144, 256, 0, stream>>>(y, yh, 8192 * 768);
  cvt_f32_f16_scale<<<576, 256, 0, stream>>>(Wq, wqh, taup, 768 * 768);
  cvt_f32_f16<<<1152, 256, 0, stream>>>(Wkv, wkh, 1536 * 768);
  cvt_f32_f16<<<576, 256, 0, stream>>>(Wproj, wph, 768 * 768);

  gemm_nt<0><<<dim3(128, 6), 128, 0, stream>>>(xh, wqh, qb, nullptr, nullptr, nullptr, 8192, 768, 768);
  gemm_nt<1><<<dim3(128, 12), 128, 0, stream>>>(yh, wkh, kb, vtb, nullptr, nullptr, 8192, 1536, 768);
  attn_kernel<<<dim3(48 * 16), 256, 0, stream>>>(qb, kb, vtb, ao);
  gemm_nt<2><<<dim3(128, 6), 128, 0, stream>>>(ao, wph, nullptr, nullptr, out, bproj, 8192, 768, 768);
}

// Round 2
// 250.925 us; speedup vs baseline: 1.0871x; 1.0871x over previous
//
#include <hip/hip_runtime.h>
#include <math.h>

typedef unsigned short u16;
typedef unsigned int u32;
typedef __fp16 fp16x2 __attribute__((ext_vector_type(2)));
typedef _Float16 half8 __attribute__((ext_vector_type(8)));
typedef float f32x4 __attribute__((ext_vector_type(4)));

#define NH   12
#define SEQ  2048
#define CDIM 768

__device__ __forceinline__ u16 f2h(float f) {
  _Float16 h = (_Float16)f;
  return __builtin_bit_cast(u16, h);
}
__device__ __forceinline__ u32 pk2(float a, float b) {
  fp16x2 h = __builtin_amdgcn_cvt_pkrtz(a, b);    // v_cvt_pk_rtz_f16_f32
  return __builtin_bit_cast(u32, h);
}
// async global->LDS DMA, 16B per lane; LDS dest = wave-uniform base + lane*16
__device__ __forceinline__ void dma16(const u16* g, u16* l) {
  __builtin_amdgcn_global_load_lds(
      (const __attribute__((address_space(1))) u32*)g,
      (__attribute__((address_space(3))) u32*)l, 16, 0, 0);
}

// ---------------- fp32 -> f16 convert (optional scale) ----------------
__global__ __launch_bounds__(256) void cvt_f32_f16(const float* __restrict__ in,
                                                   u16* __restrict__ out, int n) {
  int i = (blockIdx.x * 256 + threadIdx.x) * 4;
  if (i < n) {
    float4 f = *(const float4*)(in + i);
    *(uint2*)(out + i) = make_uint2(pk2(f.x, f.y), pk2(f.z, f.w));
  }
}
__global__ __launch_bounds__(256) void cvt_f32_f16_scale(const float* __restrict__ in,
                                                         u16* __restrict__ out,
                                                         const float* __restrict__ taup, int n) {
  float t = *taup;
  float sp = (t > 20.f) ? t : log1pf(expf(t));
  float s = (0.125f / (sp + 1e-6f)) * 1.44269504088896340736f;  // qkscale * log2(e)
  int i = (blockIdx.x * 256 + threadIdx.x) * 4;
  if (i < n) {
    float4 f = *(const float4*)(in + i);
    *(uint2*)(out + i) = make_uint2(pk2(f.x * s, f.y * s), pk2(f.z * s, f.w * s));
  }
}

// ---------------- NT GEMM: C[M,N] = A[M,K] @ B[N,K]^T, f16 MFMA, fp32 acc ---
// NEW: 128x128 tile, 4 waves (each owns a 64x64 quadrant), BK=64, 2-phase
// double-buffered global_load_lds staging (prefetch tile t+1 before compute
// of tile t, single barrier per K-step). 64 KB LDS -> 2 blocks/CU, 8 waves/CU
// (was 64x128/2-wave = 6 waves/CU with poor latency hiding).
// Staging into unpadded 128B rows with chunk-XOR swizzle (source-permuted;
// read side XORs with l16&7) -> conflict-free ds_read_b128.
// MODE 0: out0 = q [B,H,N,D] f16 (scale pre-folded into Wq)
// MODE 1: cols [0,768)->k [B,H,N,D]; [768,1536)->v transposed [B,H,D,N]
// MODE 2: fp32 out[M,N] = acc + bias[n]
template<int MODE>
__global__ __launch_bounds__(256, 2) void gemm_nt(
    const u16* __restrict__ A, const u16* __restrict__ B,
    u16* __restrict__ out0, u16* __restrict__ out1,
    float* __restrict__ outf, const float* __restrict__ bias,
    int M, int N, int K)
{
  __shared__ __align__(16) u16 As[2][128 * 64];   // [buf][m][k], swizzled, 2x16 KB
  __shared__ __align__(16) u16 Bs[2][128 * 64];   // [buf][n][k], swizzled, 2x16 KB
  const int tid = threadIdx.x;
  const int wave = tid >> 6, lane = tid & 63;
  const int quad = lane >> 4, l16 = lane & 15;
  const int wr = wave >> 1, wc = wave & 1;        // wave quadrant (64x64)
  const int row0 = blockIdx.x * 128, col0 = blockIdx.y * 128;

  const int sub = lane >> 3;                   // row within an 8-row DMA slab
  const int csw = ((lane & 7) ^ sub) * 8;      // swizzled source chunk (elems)

  f32x4 acc[4][4] = {};

  auto stage = [&](int k0, int bsel) {
    u16* Asp = As[bsel];
    u16* Bsp = Bs[bsel];
    #pragma unroll
    for (int i = 0; i < 4; i++) {
      int ii = wave * 4 + i;                   // slabs 0..15 (8 rows each)
      dma16(A + (size_t)(row0 + ii * 8 + sub) * K + k0 + csw, Asp + ii * 512);
      dma16(B + (size_t)(col0 + ii * 8 + sub) * K + k0 + csw, Bsp + ii * 512);
    }
  };

  stage(0, 0);
  __syncthreads();                             // drain tile-0 DMA

  const int nk = K >> 6;
  for (int t = 0; t < nk; t++) {
    const int cur = t & 1;
    if (t + 1 < nk) stage((t + 1) << 6, cur ^ 1);   // prefetch next tile
    const u16* Asp = As[cur];
    const u16* Bsp = Bs[cur];
    #pragma unroll
    for (int ks = 0; ks < 2; ks++) {
      half8 af[4], bfr[4];
      #pragma unroll
      for (int mt = 0; mt < 4; mt++)
        af[mt] = *(const half8*)&Asp[(wr * 64 + mt * 16 + l16) * 64 + (((ks * 4 + quad) ^ (l16 & 7)) * 8)];
      #pragma unroll
      for (int nt = 0; nt < 4; nt++)
        bfr[nt] = *(const half8*)&Bsp[(wc * 64 + nt * 16 + l16) * 64 + (((ks * 4 + quad) ^ (l16 & 7)) * 8)];
      #pragma unroll
      for (int mt = 0; mt < 4; mt++)
        #pragma unroll
        for (int nt = 0; nt < 4; nt++)
          acc[mt][nt] = __builtin_amdgcn_mfma_f32_16x16x32_f16(af[mt], bfr[nt], acc[mt][nt], 0, 0, 0);
    }
    __syncthreads();   // readers done with buf[cur]; prefetch DMA drained (vmcnt 0)
  }

  // epilogue: C layout col=lane&15, row=quad*4+reg
  #pragma unroll
  for (int mt = 0; mt < 4; mt++)
  #pragma unroll
  for (int nt = 0; nt < 4; nt++)
  #pragma unroll
  for (int r = 0; r < 4; r++) {
    int gm = row0 + wr * 64 + mt * 16 + quad * 4 + r;
    int gn = col0 + wc * 64 + nt * 16 + l16;
    float v = acc[mt][nt][r];
    if (MODE == 0) {
      int b = gm >> 11, n = gm & 2047;
      int h = gn >> 6, d = gn & 63;
      out0[(((size_t)(b * NH + h)) * SEQ + n) * 64 + d] = f2h(v);
    } else if (MODE == 1) {
      int b = gm >> 11, n = gm & 2047;
      if (gn < CDIM) {
        int h = gn >> 6, d = gn & 63;
        out0[(((size_t)(b * NH + h)) * SEQ + n) * 64 + d] = f2h(v);
      } else {
        int c = gn - CDIM;
        int h = c >> 6, d = c & 63;
        out1[(((size_t)(b * NH + h)) * 64 + d) * SEQ + n] = f2h(v);   // V^T: [B,H,D,N]
      }
    } else {
      outf[(size_t)gm * N + gn] = v + bias[gn];
    }
  }
}

// ---------------- flash attention (transposed-S, f16, no-max softmax) ------
// grid 48*(16 q-tiles of 128) = 768. 4 waves x 32 q-rows (mt=2). KV tile 64.
// 2-phase double-buffered K/V staging via global_load_lds, chunk-XOR swizzle.
// St = K Q^T so softmax rows live per-lane; fixed-shift softmax p=exp2(s).
// NEW this round:
//  - chunked XCD swizzle: XCD x gets blocks [x*96,(x+1)*96) = 6 complete
//    heads -> K/V footprint 3 MB per 4 MB L2 (was 24 MB thrash; FETCH 106MB)
//  - raw v_exp_f32 via __builtin_amdgcn_exp2f (libm exp2f has fixup code)
//  - row-sum l computed on the MATRIX pipe: extra MFMA vs ones-vector.
//    Its C layout (row=quad*4+r) matches oacc exactly -> epilogue reads
//    lacc[mt][r] directly, no shfl reduce, no 32 VALU adds/tile.
//  - s_setprio(1) around MFMA clusters (T5; +4-7% measured on attn)
__global__ __launch_bounds__(256, 3) void attn_kernel(
    const u16* __restrict__ Q, const u16* __restrict__ Kb,
    const u16* __restrict__ Vtg, u16* __restrict__ Ob)
{
  constexpr int LDP = 72;                      // Ps rows 144 B (16B-aligned)
  __shared__ __align__(16) u16 Ks[2][64 * 64];    // [buf][kk][d] swizzled, 2x8 KB
  __shared__ __align__(16) u16 Vs[2][64 * 64];    // [buf][d][kk] swizzled, 2x8 KB
  __shared__ __align__(16) u16 Ps[4 * 16 * LDP];

  // bijective chunked XCD swizzle: 768 blocks = 8 XCDs x 96
  const int bid = (blockIdx.x & 7) * 96 + (blockIdx.x >> 3);
  const int qt = bid & 15;
  const int bh = bid >> 4;
  const int b = bh / NH, h = bh % NH;
  const u16* Qp = Q   + (size_t)bh * SEQ * 64;
  const u16* Kp = Kb  + (size_t)bh * SEQ * 64;
  const u16* Vp = Vtg + (size_t)bh * 64 * SEQ;

  const int tid = threadIdx.x;
  const int wave = tid >> 6, lane = tid & 63;
  const int quad = lane >> 4, l16 = lane & 15;
  const int sub = lane >> 3;
  const int csw = ((lane & 7) ^ sub) * 8;
  u16* Pw = Ps + wave * 16 * LDP;

  half8 vone;
  #pragma unroll
  for (int j = 0; j < 8; j++) vone[j] = (_Float16)1.0f;

  // Q fragments (B-operand): Q[m=l16][d=ks*32+quad*8+j], scale pre-folded
  half8 qf[2][2];
  #pragma unroll
  for (int mt = 0; mt < 2; mt++)
    #pragma unroll
    for (int ks = 0; ks < 2; ks++)
      qf[mt][ks] = *(const half8*)(Qp + (size_t)(qt * 128 + wave * 32 + mt * 16 + l16) * 64 + ks * 32 + quad * 8);

  f32x4 oacc[2][4] = {};
  f32x4 lacc[2] = {};                          // row-sums via MFMA w/ ones

  auto stage = [&](int kt, int bsel) {
    #pragma unroll
    for (int i = 0; i < 2; i++) {
      int ii = wave * 2 + i;                   // slabs 0..7 (8 rows each)
      dma16(Kp + (size_t)(kt * 64 + ii * 8 + sub) * 64 + csw, &Ks[bsel][ii * 512]);
      dma16(Vp + (size_t)(ii * 8 + sub) * SEQ + kt * 64 + csw, &Vs[bsel][ii * 512]);
    }
  };

  stage(0, 0);
  __syncthreads();                             // drain tile-0 DMA

  for (int kt = 0; kt < SEQ / 64; kt++) {
    const int cur = kt & 1;
    if (kt + 1 < SEQ / 64) stage(kt + 1, cur ^ 1);   // prefetch next K/V tile
    const u16* Ksp = Ks[cur];
    const u16* Vsp = Vs[cur];

    // St = K Q^T : sacc[mt][ntk] holds St[kk=ntk*16+quad*4+r][m=l16]
    f32x4 sacc[2][4] = {};
    __builtin_amdgcn_s_setprio(1);
    #pragma unroll
    for (int ks = 0; ks < 2; ks++) {
      #pragma unroll
      for (int ntk = 0; ntk < 4; ntk++) {
        half8 kf = *(const half8*)&Ksp[(ntk * 16 + l16) * 64 + (((ks * 4 + quad) ^ (l16 & 7)) * 8)];
        #pragma unroll
        for (int mt = 0; mt < 2; mt++)
          sacc[mt][ntk] = __builtin_amdgcn_mfma_f32_16x16x32_f16(kf, qf[mt][ks], sacc[mt][ntk], 0, 0, 0);
      }
    }
    __builtin_amdgcn_s_setprio(0);

    // softmax (fixed shift): p = exp2(s); P -> LDS (C->A layout), per mt
    half8 pf[2][2];
    #pragma unroll
    for (int mt = 0; mt < 2; mt++) {
      #pragma unroll
      for (int ntk = 0; ntk < 4; ntk++) {
        float p0 = __builtin_amdgcn_exp2f(sacc[mt][ntk][0]);
        float p1 = __builtin_amdgcn_exp2f(sacc[mt][ntk][1]);
        float p2 = __builtin_amdgcn_exp2f(sacc[mt][ntk][2]);
        float p3 = __builtin_amdgcn_exp2f(sacc[mt][ntk][3]);
        *(uint2*)(&Pw[l16 * LDP + ntk * 16 + quad * 4]) = make_uint2(pk2(p0, p1), pk2(p2, p3));
      }
      pf[mt][0] = *(const half8*)&Pw[l16 * LDP + quad * 8];
      pf[mt][1] = *(const half8*)&Pw[l16 * LDP + 32 + quad * 8];
    }

    // O += P V (vf reused across mt); l += P 1 on the matrix pipe
    __builtin_amdgcn_s_setprio(1);
    #pragma unroll
    for (int ks = 0; ks < 2; ks++) {
      #pragma unroll
      for (int dt = 0; dt < 4; dt++) {
        half8 vf = *(const half8*)&Vsp[(dt * 16 + l16) * 64 + (((ks * 4 + quad) ^ (l16 & 7)) * 8)];
        #pragma unroll
        for (int mt = 0; mt < 2; mt++)
          oacc[mt][dt] = __builtin_amdgcn_mfma_f32_16x16x32_f16(pf[mt][ks], vf, oacc[mt][dt], 0, 0, 0);
      }
      #pragma unroll
      for (int mt = 0; mt < 2; mt++)
        lacc[mt] = __builtin_amdgcn_mfma_f32_16x16x32_f16(pf[mt][ks], vone, lacc[mt], 0, 0, 0);
    }
    __builtin_amdgcn_s_setprio(0);

    __syncthreads();   // readers done with buf[cur]; prefetch DMA drained
  }

  // epilogue: O / l -> ao[b][n][h*64+d] (f16); lacc row layout == oacc rows
  #pragma unroll
  for (int mt = 0; mt < 2; mt++) {
    #pragma unroll
    for (int r = 0; r < 4; r++) {
      float inv = 1.0f / lacc[mt][r];
      int n = qt * 128 + wave * 32 + mt * 16 + quad * 4 + r;
      size_t base = ((size_t)b * SEQ + n) * CDIM + h * 64;
      #pragma unroll
      for (int dt = 0; dt < 4; dt++)
        Ob[base + dt * 16 + l16] = f2h(oacc[mt][dt][r] * inv);
    }
  }
}

// ---------------- launch ----------------
extern "C" void kernel_launch(void* const* d_in, const int* in_sizes, int n_in,
                              void* d_out, int out_size, void* d_ws, size_t ws_size,
                              hipStream_t stream)
{
  const float* x     = (const float*)d_in[0];
  const float* y     = (const float*)d_in[1];
  const float* Wq    = (const float*)d_in[2];
  const float* Wkv   = (const float*)d_in[3];
  const float* taup  = (const float*)d_in[4];
  const float* Wproj = (const float*)d_in[5];
  const float* bproj = (const float*)d_in[6];
  float* out = (float*)d_out;

  char* ws = (char*)d_ws;
  size_t off = 0;
  auto alloc = [&](size_t bytes) { char* p = ws + off; off += bytes; return p; };
  u16* xh  = (u16*)alloc(8192ull * 768 * 2);
  u16* yh  = (u16*)alloc(8192ull * 768 * 2);
  u16* wqh = (u16*)alloc(768ull * 768 * 2);
  u16* wkh = (u16*)alloc(1536ull * 768 * 2);
  u16* wph = (u16*)alloc(768ull * 768 * 2);
  u16* qb  = (u16*)alloc(8192ull * 768 * 2);   // [B,H,N,D] f16, scale folded
  u16* kb  = (u16*)alloc(8192ull * 768 * 2);   // [B,H,N,D]
  u16* vtb = (u16*)alloc(8192ull * 768 * 2);   // [B,H,D,N]
  u16* ao  = (u16*)alloc(8192ull * 768 * 2);   // [B,N,C]

  cvt_f32_f16<<<6144, 256, 0, stream>>>(x, xh, 8192 * 768);
  cvt_f32_f16<<<6144, 256, 0, stream>>>(y, yh, 8192 * 768);
  cvt_f32_f16_scale<<<576, 256, 0, stream>>>(Wq, wqh, taup, 768 * 768);
  cvt_f32_f16<<<1152, 256, 0, stream>>>(Wkv, wkh, 1536 * 768);
  cvt_f32_f16<<<576, 256, 0, stream>>>(Wproj, wph, 768 * 768);

  gemm_nt<0><<<dim3(64, 6), 256, 0, stream>>>(xh, wqh, qb, nullptr, nullptr, nullptr, 8192, 768, 768);
  gemm_nt<1><<<dim3(64, 12), 256, 0, stream>>>(yh, wkh, kb, vtb, nullptr, nullptr, 8192, 1536, 768);
  attn_kernel<<<dim3(48 * 16), 256, 0, stream>>>(qb, kb, vtb, ao);
  gemm_nt<2><<<dim3(64, 6), 256, 0, stream>>>(ao, wph, nullptr, nullptr, out, bproj, 8192, 768, 768);
}

// Round 3
// 238.130 us; speedup vs baseline: 1.1456x; 1.0537x over previous
//
#include <hip/hip_runtime.h>
#include <math.h>

typedef unsigned short u16;
typedef unsigned int u32;
typedef __fp16 fp16x2 __attribute__((ext_vector_type(2)));
typedef _Float16 half8 __attribute__((ext_vector_type(8)));
typedef float f32x4 __attribute__((ext_vector_type(4)));

#define NH   12
#define SEQ  2048
#define CDIM 768

__device__ __forceinline__ u16 f2h(float f) {
  _Float16 h = (_Float16)f;
  return __builtin_bit_cast(u16, h);
}
__device__ __forceinline__ u32 pk2(float a, float b) {
  fp16x2 h = __builtin_amdgcn_cvt_pkrtz(a, b);    // v_cvt_pk_rtz_f16_f32
  return __builtin_bit_cast(u32, h);
}
// async global->LDS DMA, 16B per lane; LDS dest = wave-uniform base + lane*16
__device__ __forceinline__ void dma16(const u16* g, u16* l) {
  __builtin_amdgcn_global_load_lds(
      (const __attribute__((address_space(1))) u32*)g,
      (__attribute__((address_space(3))) u32*)l, 16, 0, 0);
}

// ---------------- fused fp32 -> f16 converts (x+y in one, weights in one) ---
__global__ __launch_bounds__(256) void cvt_xy(const float* __restrict__ x,
                                              const float* __restrict__ y,
                                              u16* __restrict__ xh, u16* __restrict__ yh) {
  const long NEL = 8192l * 768;
  long i = ((long)blockIdx.x * 256 + threadIdx.x) * 4;
  const float* in = (i < NEL) ? x : y;
  u16* out = (i < NEL) ? xh : yh;
  long j = (i < NEL) ? i : i - NEL;
  float4 f = *(const float4*)(in + j);
  *(uint2*)(out + j) = make_uint2(pk2(f.x, f.y), pk2(f.z, f.w));
}
// ranges are block-uniform: 576 blocks Wq (scaled), 1152 Wkv, 576 Wproj
__global__ __launch_bounds__(256) void cvt_w(const float* __restrict__ Wq,
                                             const float* __restrict__ Wkv,
                                             const float* __restrict__ Wp,
                                             const float* __restrict__ taup,
                                             u16* __restrict__ wqh, u16* __restrict__ wkh,
                                             u16* __restrict__ wph) {
  const long E1 = 768l * 768, E2 = E1 + 1536l * 768;
  long i = ((long)blockIdx.x * 256 + threadIdx.x) * 4;
  const float* in; u16* out; long j; float s;
  if (i < E1) {
    float t = *taup;
    float sp = (t > 20.f) ? t : log1pf(expf(t));
    s = (0.125f / (sp + 1e-6f)) * 1.44269504088896340736f;  // qkscale * log2(e)
    in = Wq; out = wqh; j = i;
  } else if (i < E2) {
    s = 1.f; in = Wkv; out = wkh; j = i - E1;
  } else {
    s = 1.f; in = Wp; out = wph; j = i - E2;
  }
  float4 f = *(const float4*)(in + j);
  *(uint2*)(out + j) = make_uint2(pk2(f.x * s, f.y * s), pk2(f.z * s, f.w * s));
}

// ---------------- NT GEMM: C[M,N] = A[M,K] @ B[N,K]^T, f16 MFMA, fp32 acc ---
// Tile 128(M) x 64(N), BK=64, K=768 fixed (12 iters). 4 waves as 2x2 quadrants
// (each wave 64x32 -> acc[4][2]). 48 KB LDS -> 3 blocks/CU = 12 waves/CU (was
// 1.5-3 blocks total residency with the 128x128 grid-starved layout).
// 2-phase double-buffered global_load_lds staging, chunk-XOR swizzle.
// MODE 0: FUSED QKV. by<12: A=xh,B=Wq -> q [B,H,N,D] (scale pre-folded);
//         by>=12: A=yh,B=Wkv -> cols[0,768) k [B,H,N,D]; [768,1536) v^T [B,H,D,N]
//         (v^T stored as 8B uint2: 4 consecutive n per lane -> 4x fewer
//          scattered-write transactions than 2B stores)
// MODE 2: A=ao,B=Wproj -> fp32 out[M,768] = acc + bias[n]
template<int MODE>
__global__ __launch_bounds__(256, 3) void gemm_k(
    const u16* __restrict__ A0, const u16* __restrict__ A1,
    const u16* __restrict__ B0, const u16* __restrict__ B1,
    u16* __restrict__ oq, u16* __restrict__ ok, u16* __restrict__ ovt,
    float* __restrict__ outf, const float* __restrict__ bias)
{
  __shared__ __align__(16) u16 As[2][128 * 64];   // [buf][m][k] swizzled, 32 KB
  __shared__ __align__(16) u16 Bs[2][64 * 64];    // [buf][n][k] swizzled, 16 KB
  const int tid = threadIdx.x;
  const int wave = tid >> 6, lane = tid & 63;
  const int quad = lane >> 4, l16 = lane & 15;
  const int wr = wave >> 1, wc = wave & 1;        // wave quadrant (64m x 32n)
  const int row0 = blockIdx.x * 128;
  const int by = blockIdx.y;

  const u16* A; const u16* Bm; int cb;
  if (MODE == 0) {
    if (by < 12) { A = A0; Bm = B0; cb = by; }
    else         { A = A1; Bm = B1; cb = by - 12; }
  } else {
    A = A0; Bm = B0; cb = by;
  }
  const int col0 = cb * 64;

  const int sub = lane >> 3;                   // row within an 8-row DMA slab
  const int csw = ((lane & 7) ^ sub) * 8;      // swizzled source chunk (elems)

  f32x4 acc[4][2] = {};

  auto stage = [&](int k0, int bsel) {
    #pragma unroll
    for (int i = 0; i < 4; i++) {
      int ii = wave * 4 + i;                   // A slabs 0..15 (8 rows each)
      dma16(A + (size_t)(row0 + ii * 8 + sub) * 768 + k0 + csw, &As[bsel][ii * 512]);
    }
    #pragma unroll
    for (int i = 0; i < 2; i++) {
      int ii = wave * 2 + i;                   // B slabs 0..7
      dma16(Bm + (size_t)(col0 + ii * 8 + sub) * 768 + k0 + csw, &Bs[bsel][ii * 512]);
    }
  };

  stage(0, 0);
  __syncthreads();                             // drain tile-0 DMA

  #pragma unroll 1
  for (int t = 0; t < 12; t++) {
    const int cur = t & 1;
    if (t + 1 < 12) stage((t + 1) << 6, cur ^ 1);   // prefetch next tile
    const u16* Asp = As[cur];
    const u16* Bsp = Bs[cur];
    #pragma unroll
    for (int ks = 0; ks < 2; ks++) {
      half8 af[4], bfr[2];
      #pragma unroll
      for (int mt = 0; mt < 4; mt++)
        af[mt] = *(const half8*)&Asp[(wr * 64 + mt * 16 + l16) * 64 + (((ks * 4 + quad) ^ (l16 & 7)) * 8)];
      #pragma unroll
      for (int nt = 0; nt < 2; nt++)
        bfr[nt] = *(const half8*)&Bsp[(wc * 32 + nt * 16 + l16) * 64 + (((ks * 4 + quad) ^ (l16 & 7)) * 8)];
      #pragma unroll
      for (int mt = 0; mt < 4; mt++)
        #pragma unroll
        for (int nt = 0; nt < 2; nt++)
          acc[mt][nt] = __builtin_amdgcn_mfma_f32_16x16x32_f16(af[mt], bfr[nt], acc[mt][nt], 0, 0, 0);
    }
    __syncthreads();   // readers done with buf[cur]; prefetch DMA drained
  }

  // epilogue: C layout col=lane&15, row=quad*4+reg
  #pragma unroll
  for (int mt = 0; mt < 4; mt++)
  #pragma unroll
  for (int nt = 0; nt < 2; nt++) {
    int gm0 = row0 + wr * 64 + mt * 16 + quad * 4;
    int gn = col0 + wc * 32 + nt * 16 + l16;
    f32x4 v = acc[mt][nt];
    if (MODE == 0) {
      int b = gm0 >> 11, n0 = gm0 & 2047;
      if (by < 12) {
        int h = gn >> 6, d = gn & 63;
        size_t base = (((size_t)(b * NH + h)) * SEQ + n0) * 64 + d;
        #pragma unroll
        for (int r = 0; r < 4; r++) oq[base + (size_t)r * 64] = f2h(v[r]);
      } else if (gn < CDIM) {
        int h = gn >> 6, d = gn & 63;
        size_t base = (((size_t)(b * NH + h)) * SEQ + n0) * 64 + d;
        #pragma unroll
        for (int r = 0; r < 4; r++) ok[base + (size_t)r * 64] = f2h(v[r]);
      } else {
        int c = gn - CDIM;
        int h = c >> 6, d = c & 63;
        *(uint2*)&ovt[(((size_t)(b * NH + h)) * 64 + d) * SEQ + n0] =
            make_uint2(pk2(v[0], v[1]), pk2(v[2], v[3]));   // V^T: 4 consecutive n
      }
    } else {
      float bv = bias[gn];
      #pragma unroll
      for (int r = 0; r < 4; r++)
        outf[(size_t)(gm0 + r) * CDIM + gn] = v[r] + bv;
    }
  }
}

// ---------------- flash attention (transposed-S, f16, no-max softmax) ------
// QBLK=64: grid 48 heads x 32 q-tiles = 1536 blocks (chunked XCD swizzle:
// 192 blocks = 6 whole heads per XCD -> 3 MB K/V per L2). 4 waves x 16 q-rows.
// LDS 40 KB exactly -> 4 blocks/CU residency (16 waves/CU, was 8.5).
// K/V 2-phase double-buffered via global_load_lds, chunk-XOR swizzle.
// St = K Q^T so softmax rows live per-lane; fixed-shift softmax p=exp2(s).
// Ps is now chunk-XOR swizzled 64-elem rows (was linear stride-72): P-writes
// hit every bank evenly (was even-banks-only, 2x write conflict cost).
// Row-sum l on the matrix pipe (MFMA vs ones). s_setprio around MFMA clusters.
__global__ __launch_bounds__(256, 4) void attn_kernel(
    const u16* __restrict__ Q, const u16* __restrict__ Kb,
    const u16* __restrict__ Vtg, u16* __restrict__ Ob)
{
  __shared__ __align__(16) u16 Ks[2][64 * 64];    // [buf][kk][d] swizzled, 2x8 KB
  __shared__ __align__(16) u16 Vs[2][64 * 64];    // [buf][d][kk] swizzled, 2x8 KB
  __shared__ __align__(16) u16 Ps[4 * 16 * 64];   // per-wave 16x64, swizzled, 8 KB

  // bijective chunked XCD swizzle: 1536 blocks = 8 XCDs x 192
  const int bid = (blockIdx.x & 7) * 192 + (blockIdx.x >> 3);
  const int qt = bid & 31;
  const int bh = bid >> 5;
  const int b = bh / NH, h = bh % NH;
  const u16* Qp = Q   + (size_t)bh * SEQ * 64;
  const u16* Kp = Kb  + (size_t)bh * SEQ * 64;
  const u16* Vp = Vtg + (size_t)bh * 64 * SEQ;

  const int tid = threadIdx.x;
  const int wave = tid >> 6, lane = tid & 63;
  const int quad = lane >> 4, l16 = lane & 15;
  const int sub = lane >> 3;
  const int csw = ((lane & 7) ^ sub) * 8;
  u16* Pw = Ps + wave * 16 * 64;

  half8 vone;
  #pragma unroll
  for (int j = 0; j < 8; j++) vone[j] = (_Float16)1.0f;

  // Q fragments (B-operand): Q[m=l16][d=ks*32+quad*8+j], scale pre-folded
  half8 qf[2];
  #pragma unroll
  for (int ks = 0; ks < 2; ks++)
    qf[ks] = *(const half8*)(Qp + (size_t)(qt * 64 + wave * 16 + l16) * 64 + ks * 32 + quad * 8);

  f32x4 oacc[4] = {};
  f32x4 lacc = {};                             // row-sums via MFMA w/ ones

  auto stage = [&](int kt, int bsel) {
    #pragma unroll
    for (int i = 0; i < 2; i++) {
      int ii = wave * 2 + i;                   // slabs 0..7 (8 rows each)
      dma16(Kp + (size_t)(kt * 64 + ii * 8 + sub) * 64 + csw, &Ks[bsel][ii * 512]);
      dma16(Vp + (size_t)(ii * 8 + sub) * SEQ + kt * 64 + csw, &Vs[bsel][ii * 512]);
    }
  };

  stage(0, 0);
  __syncthreads();                             // drain tile-0 DMA

  for (int kt = 0; kt < SEQ / 64; kt++) {
    const int cur = kt & 1;
    if (kt + 1 < SEQ / 64) stage(kt + 1, cur ^ 1);   // prefetch next K/V tile
    const u16* Ksp = Ks[cur];
    const u16* Vsp = Vs[cur];

    // St = K Q^T : sacc[ntk] holds St[kk=ntk*16+quad*4+r][m=l16]
    f32x4 sacc[4] = {};
    __builtin_amdgcn_s_setprio(1);
    #pragma unroll
    for (int ks = 0; ks < 2; ks++) {
      #pragma unroll
      for (int ntk = 0; ntk < 4; ntk++) {
        half8 kf = *(const half8*)&Ksp[(ntk * 16 + l16) * 64 + (((ks * 4 + quad) ^ (l16 & 7)) * 8)];
        sacc[ntk] = __builtin_amdgcn_mfma_f32_16x16x32_f16(kf, qf[ks], sacc[ntk], 0, 0, 0);
      }
    }
    __builtin_amdgcn_s_setprio(0);

    // softmax (fixed shift): p = exp2(s); P -> swizzled Ps (C->A layout)
    // write chunk c = kk>>3 at c^(l16&7); half (quad&1) selects 8B within 16B
    #pragma unroll
    for (int ntk = 0; ntk < 4; ntk++) {
      float p0 = __builtin_amdgcn_exp2f(sacc[ntk][0]);
      float p1 = __builtin_amdgcn_exp2f(sacc[ntk][1]);
      float p2 = __builtin_amdgcn_exp2f(sacc[ntk][2]);
      float p3 = __builtin_amdgcn_exp2f(sacc[ntk][3]);
      *(uint2*)&Pw[l16 * 64 + (((ntk * 2 + (quad >> 1)) ^ (l16 & 7)) * 8) + (quad & 1) * 4] =
          make_uint2(pk2(p0, p1), pk2(p2, p3));
    }
    half8 pf[2];
    #pragma unroll
    for (int ks = 0; ks < 2; ks++)
      pf[ks] = *(const half8*)&Pw[l16 * 64 + (((ks * 4 + quad) ^ (l16 & 7)) * 8)];

    // O += P V (A-operand pf, B-operand vf); l += P 1 on the matrix pipe
    __builtin_amdgcn_s_setprio(1);
    #pragma unroll
    for (int ks = 0; ks < 2; ks++) {
      #pragma unroll
      for (int dt = 0; dt < 4; dt++) {
        half8 vf = *(const half8*)&Vsp[(dt * 16 + l16) * 64 + (((ks * 4 + quad) ^ (l16 & 7)) * 8)];
        oacc[dt] = __builtin_amdgcn_mfma_f32_16x16x32_f16(pf[ks], vf, oacc[dt], 0, 0, 0);
      }
      lacc = __builtin_amdgcn_mfma_f32_16x16x32_f16(pf[ks], vone, lacc, 0, 0, 0);
    }
    __builtin_amdgcn_s_setprio(0);

    __syncthreads();   // readers done with buf[cur]; prefetch DMA drained
  }

  // epilogue: O / l -> ao[b][n][h*64+d] (f16); lacc row layout == oacc rows
  #pragma unroll
  for (int r = 0; r < 4; r++) {
    float inv = 1.0f / lacc[r];
    int n = qt * 64 + wave * 16 + quad * 4 + r;
    size_t base = ((size_t)b * SEQ + n) * CDIM + h * 64;
    #pragma unroll
    for (int dt = 0; dt < 4; dt++)
      Ob[base + dt * 16 + l16] = f2h(oacc[dt][r] * inv);
  }
}

// ---------------- launch ----------------
extern "C" void kernel_launch(void* const* d_in, const int* in_sizes, int n_in,
                              void* d_out, int out_size, void* d_ws, size_t ws_size,
                              hipStream_t stream)
{
  const float* x     = (const float*)d_in[0];
  const float* y     = (const float*)d_in[1];
  const float* Wq    = (const float*)d_in[2];
  const float* Wkv   = (const float*)d_in[3];
  const float* taup  = (const float*)d_in[4];
  const float* Wproj = (const float*)d_in[5];
  const float* bproj = (const float*)d_in[6];
  float* out = (float*)d_out;

  char* ws = (char*)d_ws;
  size_t off = 0;
  auto alloc = [&](size_t bytes) { char* p = ws + off; off += bytes; return p; };
  u16* xh  = (u16*)alloc(8192ull * 768 * 2);
  u16* yh  = (u16*)alloc(8192ull * 768 * 2);
  u16* wqh = (u16*)alloc(768ull * 768 * 2);
  u16* wkh = (u16*)alloc(1536ull * 768 * 2);
  u16* wph = (u16*)alloc(768ull * 768 * 2);
  u16* qb  = (u16*)alloc(8192ull * 768 * 2);   // [B,H,N,D] f16, scale folded
  u16* kb  = (u16*)alloc(8192ull * 768 * 2);   // [B,H,N,D]
  u16* vtb = (u16*)alloc(8192ull * 768 * 2);   // [B,H,D,N]
  u16* ao  = (u16*)alloc(8192ull * 768 * 2);   // [B,N,C]

  cvt_xy<<<12288, 256, 0, stream>>>(x, y, xh, yh);
  cvt_w<<<2304, 256, 0, stream>>>(Wq, Wkv, Wproj, taup, wqh, wkh, wph);

  // fused QKV GEMM: by<12 -> Q (N=768), by in [12,36) -> KV (N=1536)
  gemm_k<0><<<dim3(64, 36), 256, 0, stream>>>(xh, yh, wqh, wkh, qb, kb, vtb, nullptr, nullptr);
  attn_kernel<<<dim3(1536), 256, 0, stream>>>(qb, kb, vtb, ao);
  gemm_k<2><<<dim3(64, 12), 256, 0, stream>>>(ao, nullptr, wph, nullptr, nullptr, nullptr, nullptr, out, bproj);
}

// Round 4
// 229.971 us; speedup vs baseline: 1.1862x; 1.0355x over previous
//
#include <hip/hip_runtime.h>
#include <math.h>

typedef unsigned short u16;
typedef unsigned int u32;
typedef __fp16 fp16x2 __attribute__((ext_vector_type(2)));
typedef _Float16 half8 __attribute__((ext_vector_type(8)));
typedef float f32x4 __attribute__((ext_vector_type(4)));

#define NH   12
#define SEQ  2048
#define CDIM 768

__device__ __forceinline__ u16 f2h(float f) {
  _Float16 h = (_Float16)f;
  return __builtin_bit_cast(u16, h);
}
__device__ __forceinline__ u32 pk2(float a, float b) {
  fp16x2 h = __builtin_amdgcn_cvt_pkrtz(a, b);    // v_cvt_pk_rtz_f16_f32
  return __builtin_bit_cast(u32, h);
}
// async global->LDS DMA, 16B per lane; LDS dest = wave-uniform base + lane*16
__device__ __forceinline__ void dma16(const u16* g, u16* l) {
  __builtin_amdgcn_global_load_lds(
      (const __attribute__((address_space(1))) u32*)g,
      (__attribute__((address_space(3))) u32*)l, 16, 0, 0);
}

// ---------------- fused fp32 -> f16 converts (x+y in one, weights in one) ---
__global__ __launch_bounds__(256) void cvt_xy(const float* __restrict__ x,
                                              const float* __restrict__ y,
                                              u16* __restrict__ xh, u16* __restrict__ yh) {
  const long NEL = 8192l * 768;
  long i = ((long)blockIdx.x * 256 + threadIdx.x) * 4;
  const float* in = (i < NEL) ? x : y;
  u16* out = (i < NEL) ? xh : yh;
  long j = (i < NEL) ? i : i - NEL;
  float4 f = *(const float4*)(in + j);
  *(uint2*)(out + j) = make_uint2(pk2(f.x, f.y), pk2(f.z, f.w));
}
// ranges are block-uniform: 576 blocks Wq (scaled), 1152 Wkv, 576 Wproj
__global__ __launch_bounds__(256) void cvt_w(const float* __restrict__ Wq,
                                             const float* __restrict__ Wkv,
                                             const float* __restrict__ Wp,
                                             const float* __restrict__ taup,
                                             u16* __restrict__ wqh, u16* __restrict__ wkh,
                                             u16* __restrict__ wph) {
  const long E1 = 768l * 768, E2 = E1 + 1536l * 768;
  long i = ((long)blockIdx.x * 256 + threadIdx.x) * 4;
  const float* in; u16* out; long j; float s;
  if (i < E1) {
    float t = *taup;
    float sp = (t > 20.f) ? t : log1pf(expf(t));
    s = (0.125f / (sp + 1e-6f)) * 1.44269504088896340736f;  // qkscale * log2(e)
    in = Wq; out = wqh; j = i;
  } else if (i < E2) {
    s = 1.f; in = Wkv; out = wkh; j = i - E1;
  } else {
    s = 1.f; in = Wp; out = wph; j = i - E2;
  }
  float4 f = *(const float4*)(in + j);
  *(uint2*)(out + j) = make_uint2(pk2(f.x * s, f.y * s), pk2(f.z * s, f.w * s));
}

// ---------------- NT GEMM: C[M,N] = A[M,K] @ B[N,K]^T, f16 MFMA, fp32 acc ---
// Tile 128(M) x BN(N), BK=64, K=768 (12 iters). 4 waves as 2x2 quadrants,
// each wave 64 x BN/2 (acc[4][BN/32]). BN=128: 16 ds_read per 32 MFMA per
// K-step (1:2 intensity, the m97-class shape); BN=64 for the grid-starved
// proj GEMM (N=768 -> 768 blocks at BN=64 vs 384 at BN=128).
// 2-phase double-buffered global_load_lds staging, chunk-XOR swizzle.
// Linear bid already gives xcd = bx&7 (64*by % 8 == 0) -> A-panel L2 locality.
// MODE 0: FUSED QKV. by<6: A=xh,B=Wq -> q [B,H,N,D] (scale pre-folded);
//         by>=6: A=yh,B=Wkv -> cols[0,768) k [B,H,N,D]; [768,1536) v^T [B,H,D,N]
//         (v^T stored as 8B uint2: 4 consecutive n per lane)
// MODE 2: A=ao,B=Wproj -> fp32 out[M,768] = acc + bias[n]
template<int MODE, int BN, int WPB>
__global__ __launch_bounds__(256, WPB) void gemm_k(
    const u16* __restrict__ A0, const u16* __restrict__ A1,
    const u16* __restrict__ B0, const u16* __restrict__ B1,
    u16* __restrict__ oq, u16* __restrict__ ok, u16* __restrict__ ovt,
    float* __restrict__ outf, const float* __restrict__ bias)
{
  constexpr int NT = BN / 32;                     // n-tiles per wave
  __shared__ __align__(16) u16 As[2][128 * 64];   // [buf][m][k] swizzled, 32 KB
  __shared__ __align__(16) u16 Bs[2][BN * 64];    // [buf][n][k] swizzled
  const int tid = threadIdx.x;
  const int wave = tid >> 6, lane = tid & 63;
  const int quad = lane >> 4, l16 = lane & 15;
  const int wr = wave >> 1, wc = wave & 1;        // wave quadrant (64m x BN/2)
  const int row0 = blockIdx.x * 128;
  const int by = blockIdx.y;

  const u16* A; const u16* Bm; int cb;
  if (MODE == 0) {
    if (by < 6) { A = A0; Bm = B0; cb = by; }
    else        { A = A1; Bm = B1; cb = by - 6; }
  } else {
    A = A0; Bm = B0; cb = by;
  }
  const int col0 = cb * BN;

  const int sub = lane >> 3;                   // row within an 8-row DMA slab
  const int csw = ((lane & 7) ^ sub) * 8;      // swizzled source chunk (elems)

  f32x4 acc[4][NT] = {};

  auto stage = [&](int k0, int bsel) {
    #pragma unroll
    for (int i = 0; i < 4; i++) {
      int ii = wave * 4 + i;                   // A slabs 0..15 (8 rows each)
      dma16(A + (size_t)(row0 + ii * 8 + sub) * 768 + k0 + csw, &As[bsel][ii * 512]);
    }
    #pragma unroll
    for (int i = 0; i < BN / 32; i++) {
      int ii = wave * (BN / 32) + i;           // B slabs 0..BN/8-1
      dma16(Bm + (size_t)(col0 + ii * 8 + sub) * 768 + k0 + csw, &Bs[bsel][ii * 512]);
    }
  };

  stage(0, 0);
  __syncthreads();                             // drain tile-0 DMA

  #pragma unroll 1
  for (int t = 0; t < 12; t++) {
    const int cur = t & 1;
    if (t + 1 < 12) stage((t + 1) << 6, cur ^ 1);   // prefetch next tile
    const u16* Asp = As[cur];
    const u16* Bsp = Bs[cur];
    #pragma unroll
    for (int ks = 0; ks < 2; ks++) {
      half8 af[4], bfr[NT];
      #pragma unroll
      for (int mt = 0; mt < 4; mt++)
        af[mt] = *(const half8*)&Asp[(wr * 64 + mt * 16 + l16) * 64 + (((ks * 4 + quad) ^ (l16 & 7)) * 8)];
      #pragma unroll
      for (int nt = 0; nt < NT; nt++)
        bfr[nt] = *(const half8*)&Bsp[(wc * (BN / 2) + nt * 16 + l16) * 64 + (((ks * 4 + quad) ^ (l16 & 7)) * 8)];
      #pragma unroll
      for (int mt = 0; mt < 4; mt++)
        #pragma unroll
        for (int nt = 0; nt < NT; nt++)
          acc[mt][nt] = __builtin_amdgcn_mfma_f32_16x16x32_f16(af[mt], bfr[nt], acc[mt][nt], 0, 0, 0);
    }
    __syncthreads();   // readers done with buf[cur]; prefetch DMA drained
  }

  // epilogue: C layout col=lane&15, row=quad*4+reg
  #pragma unroll
  for (int mt = 0; mt < 4; mt++)
  #pragma unroll
  for (int nt = 0; nt < NT; nt++) {
    int gm0 = row0 + wr * 64 + mt * 16 + quad * 4;
    int gn = col0 + wc * (BN / 2) + nt * 16 + l16;
    f32x4 v = acc[mt][nt];
    if (MODE == 0) {
      int b = gm0 >> 11, n0 = gm0 & 2047;
      if (by < 6) {
        int h = gn >> 6, d = gn & 63;
        size_t base = (((size_t)(b * NH + h)) * SEQ + n0) * 64 + d;
        #pragma unroll
        for (int r = 0; r < 4; r++) oq[base + (size_t)r * 64] = f2h(v[r]);
      } else if (gn < CDIM) {
        int h = gn >> 6, d = gn & 63;
        size_t base = (((size_t)(b * NH + h)) * SEQ + n0) * 64 + d;
        #pragma unroll
        for (int r = 0; r < 4; r++) ok[base + (size_t)r * 64] = f2h(v[r]);
      } else {
        int c = gn - CDIM;
        int h = c >> 6, d = c & 63;
        *(uint2*)&ovt[(((size_t)(b * NH + h)) * 64 + d) * SEQ + n0] =
            make_uint2(pk2(v[0], v[1]), pk2(v[2], v[3]));   // V^T: 4 consecutive n
      }
    } else {
      float bv = bias[gn];
      #pragma unroll
      for (int r = 0; r < 4; r++)
        outf[(size_t)(gm0 + r) * CDIM + gn] = v[r] + bv;
    }
  }
}

// ---------------- flash attention (transposed-S, f16, no-max softmax) ------
// REVERTED to QBLK=128 (round-3's QBLK=64 halved per-tile intensity: 2x
// staging+barriers for same MFMA -> 68->84 us). grid 48*16 = 768 blocks,
// chunked XCD swizzle (96 blocks = 6 whole heads per XCD -> 3 MB K/V per L2).
// 4 waves x 32 q-rows (mt=2). KV tile 64, 2-phase double-buffered staging.
// KEPT from round 3: chunk-XOR swizzled Ps (16x64 per wave; write = minimal
// 4-bank occupancy, read matches K/V pattern) -> LDS 40960.
// St = K Q^T; fixed-shift softmax p=exp2(s); row-sum l on matrix pipe.
__global__ __launch_bounds__(256, 3) void attn_kernel(
    const u16* __restrict__ Q, const u16* __restrict__ Kb,
    const u16* __restrict__ Vtg, u16* __restrict__ Ob)
{
  __shared__ __align__(16) u16 Ks[2][64 * 64];    // [buf][kk][d] swizzled, 2x8 KB
  __shared__ __align__(16) u16 Vs[2][64 * 64];    // [buf][d][kk] swizzled, 2x8 KB
  __shared__ __align__(16) u16 Ps[4 * 16 * 64];   // per-wave 16x64 swizzled, 8 KB

  // bijective chunked XCD swizzle: 768 blocks = 8 XCDs x 96
  const int bid = (blockIdx.x & 7) * 96 + (blockIdx.x >> 3);
  const int qt = bid & 15;
  const int bh = bid >> 4;
  const int b = bh / NH, h = bh % NH;
  const u16* Qp = Q   + (size_t)bh * SEQ * 64;
  const u16* Kp = Kb  + (size_t)bh * SEQ * 64;
  const u16* Vp = Vtg + (size_t)bh * 64 * SEQ;

  const int tid = threadIdx.x;
  const int wave = tid >> 6, lane = tid & 63;
  const int quad = lane >> 4, l16 = lane & 15;
  const int sub = lane >> 3;
  const int csw = ((lane & 7) ^ sub) * 8;
  u16* Pw = Ps + wave * 16 * 64;

  half8 vone;
  #pragma unroll
  for (int j = 0; j < 8; j++) vone[j] = (_Float16)1.0f;

  // Q fragments (B-operand): Q[m=l16][d=ks*32+quad*8+j], scale pre-folded
  half8 qf[2][2];
  #pragma unroll
  for (int mt = 0; mt < 2; mt++)
    #pragma unroll
    for (int ks = 0; ks < 2; ks++)
      qf[mt][ks] = *(const half8*)(Qp + (size_t)(qt * 128 + wave * 32 + mt * 16 + l16) * 64 + ks * 32 + quad * 8);

  f32x4 oacc[2][4] = {};
  f32x4 lacc[2] = {};                          // row-sums via MFMA w/ ones

  auto stage = [&](int kt, int bsel) {
    #pragma unroll
    for (int i = 0; i < 2; i++) {
      int ii = wave * 2 + i;                   // slabs 0..7 (8 rows each)
      dma16(Kp + (size_t)(kt * 64 + ii * 8 + sub) * 64 + csw, &Ks[bsel][ii * 512]);
      dma16(Vp + (size_t)(ii * 8 + sub) * SEQ + kt * 64 + csw, &Vs[bsel][ii * 512]);
    }
  };

  stage(0, 0);
  __syncthreads();                             // drain tile-0 DMA

  for (int kt = 0; kt < SEQ / 64; kt++) {
    const int cur = kt & 1;
    if (kt + 1 < SEQ / 64) stage(kt + 1, cur ^ 1);   // prefetch next K/V tile
    const u16* Ksp = Ks[cur];
    const u16* Vsp = Vs[cur];

    // St = K Q^T : sacc[mt][ntk] holds St[kk=ntk*16+quad*4+r][m=l16]
    f32x4 sacc[2][4] = {};
    __builtin_amdgcn_s_setprio(1);
    #pragma unroll
    for (int ks = 0; ks < 2; ks++) {
      #pragma unroll
      for (int ntk = 0; ntk < 4; ntk++) {
        half8 kf = *(const half8*)&Ksp[(ntk * 16 + l16) * 64 + (((ks * 4 + quad) ^ (l16 & 7)) * 8)];
        #pragma unroll
        for (int mt = 0; mt < 2; mt++)
          sacc[mt][ntk] = __builtin_amdgcn_mfma_f32_16x16x32_f16(kf, qf[mt][ks], sacc[mt][ntk], 0, 0, 0);
      }
    }
    __builtin_amdgcn_s_setprio(0);

    // softmax (fixed shift): p = exp2(s); P -> swizzled Ps (C->A layout), per mt
    half8 pf[2][2];
    #pragma unroll
    for (int mt = 0; mt < 2; mt++) {
      #pragma unroll
      for (int ntk = 0; ntk < 4; ntk++) {
        float p0 = __builtin_amdgcn_exp2f(sacc[mt][ntk][0]);
        float p1 = __builtin_amdgcn_exp2f(sacc[mt][ntk][1]);
        float p2 = __builtin_amdgcn_exp2f(sacc[mt][ntk][2]);
        float p3 = __builtin_amdgcn_exp2f(sacc[mt][ntk][3]);
        *(uint2*)&Pw[l16 * 64 + (((ntk * 2 + (quad >> 1)) ^ (l16 & 7)) * 8) + (quad & 1) * 4] =
            make_uint2(pk2(p0, p1), pk2(p2, p3));
      }
      pf[mt][0] = *(const half8*)&Pw[l16 * 64 + ((quad ^ (l16 & 7)) * 8)];
      pf[mt][1] = *(const half8*)&Pw[l16 * 64 + (((4 + quad) ^ (l16 & 7)) * 8)];
    }

    // O += P V (vf reused across mt); l += P 1 on the matrix pipe
    __builtin_amdgcn_s_setprio(1);
    #pragma unroll
    for (int ks = 0; ks < 2; ks++) {
      #pragma unroll
      for (int dt = 0; dt < 4; dt++) {
        half8 vf = *(const half8*)&Vsp[(dt * 16 + l16) * 64 + (((ks * 4 + quad) ^ (l16 & 7)) * 8)];
        #pragma unroll
        for (int mt = 0; mt < 2; mt++)
          oacc[mt][dt] = __builtin_amdgcn_mfma_f32_16x16x32_f16(pf[mt][ks], vf, oacc[mt][dt], 0, 0, 0);
      }
      #pragma unroll
      for (int mt = 0; mt < 2; mt++)
        lacc[mt] = __builtin_amdgcn_mfma_f32_16x16x32_f16(pf[mt][ks], vone, lacc[mt], 0, 0, 0);
    }
    __builtin_amdgcn_s_setprio(0);

    __syncthreads();   // readers done with buf[cur]; prefetch DMA drained
  }

  // epilogue: O / l -> ao[b][n][h*64+d] (f16); lacc row layout == oacc rows
  #pragma unroll
  for (int mt = 0; mt < 2; mt++) {
    #pragma unroll
    for (int r = 0; r < 4; r++) {
      float inv = 1.0f / lacc[mt][r];
      int n = qt * 128 + wave * 32 + mt * 16 + quad * 4 + r;
      size_t base = ((size_t)b * SEQ + n) * CDIM + h * 64;
      #pragma unroll
      for (int dt = 0; dt < 4; dt++)
        Ob[base + dt * 16 + l16] = f2h(oacc[mt][dt][r] * inv);
    }
  }
}

// ---------------- launch ----------------
extern "C" void kernel_launch(void* const* d_in, const int* in_sizes, int n_in,
                              void* d_out, int out_size, void* d_ws, size_t ws_size,
                              hipStream_t stream)
{
  const float* x     = (const float*)d_in[0];
  const float* y     = (const float*)d_in[1];
  const float* Wq    = (const float*)d_in[2];
  const float* Wkv   = (const float*)d_in[3];
  const float* taup  = (const float*)d_in[4];
  const float* Wproj = (const float*)d_in[5];
  const float* bproj = (const float*)d_in[6];
  float* out = (float*)d_out;

  char* ws = (char*)d_ws;
  size_t off = 0;
  auto alloc = [&](size_t bytes) { char* p = ws + off; off += bytes; return p; };
  u16* xh  = (u16*)alloc(8192ull * 768 * 2);
  u16* yh  = (u16*)alloc(8192ull * 768 * 2);
  u16* wqh = (u16*)alloc(768ull * 768 * 2);
  u16* wkh = (u16*)alloc(1536ull * 768 * 2);
  u16* wph = (u16*)alloc(768ull * 768 * 2);
  u16* qb  = (u16*)alloc(8192ull * 768 * 2);   // [B,H,N,D] f16, scale folded
  u16* kb  = (u16*)alloc(8192ull * 768 * 2);   // [B,H,N,D]
  u16* vtb = (u16*)alloc(8192ull * 768 * 2);   // [B,H,D,N]
  u16* ao  = (u16*)alloc(8192ull * 768 * 2);   // [B,N,C]

  cvt_xy<<<12288, 256, 0, stream>>>(x, y, xh, yh);
  cvt_w<<<2304, 256, 0, stream>>>(Wq, Wkv, Wproj, taup, wqh, wkh, wph);

  // fused QKV GEMM: by<6 -> Q (N=768), by in [6,18) -> KV (N=1536), BN=128
  gemm_k<0, 128, 2><<<dim3(64, 18), 256, 0, stream>>>(xh, yh, wqh, wkh, qb, kb, vtb, nullptr, nullptr);
  attn_kernel<<<dim3(768), 256, 0, stream>>>(qb, kb, vtb, ao);
  gemm_k<2, 64, 3><<<dim3(64, 12), 256, 0, stream>>>(ao, nullptr, wph, nullptr, nullptr, nullptr, nullptr, out, bproj);
}

// Round 5
// 228.919 us; speedup vs baseline: 1.1917x; 1.0046x over previous
//
#include <hip/hip_runtime.h>
#include <math.h>

typedef unsigned short u16;
typedef unsigned int u32;
typedef __fp16 fp16x2 __attribute__((ext_vector_type(2)));
typedef _Float16 half8 __attribute__((ext_vector_type(8)));
typedef float f32x4 __attribute__((ext_vector_type(4)));

#define NH   12
#define SEQ  2048
#define CDIM 768

__device__ __forceinline__ u16 f2h(float f) {
  _Float16 h = (_Float16)f;
  return __builtin_bit_cast(u16, h);
}
__device__ __forceinline__ u32 pk2(float a, float b) {
  fp16x2 h = __builtin_amdgcn_cvt_pkrtz(a, b);    // v_cvt_pk_rtz_f16_f32
  return __builtin_bit_cast(u32, h);
}
// async global->LDS DMA, 16B per lane; LDS dest = wave-uniform base + lane*16
__device__ __forceinline__ void dma16(const u16* g, u16* l) {
  __builtin_amdgcn_global_load_lds(
      (const __attribute__((address_space(1))) u32*)g,
      (__attribute__((address_space(3))) u32*)l, 16, 0, 0);
}

// ---------------- weight converts (small, L2-resident) ----------------
// 576 blocks Wq (scaled), 1152 Wkv, 576 Wproj
__global__ __launch_bounds__(256) void cvt_w(const float* __restrict__ Wq,
                                             const float* __restrict__ Wkv,
                                             const float* __restrict__ Wp,
                                             const float* __restrict__ taup,
                                             u16* __restrict__ wqh, u16* __restrict__ wkh,
                                             u16* __restrict__ wph) {
  const long E1 = 768l * 768, E2 = E1 + 1536l * 768;
  long i = ((long)blockIdx.x * 256 + threadIdx.x) * 4;
  const float* in; u16* out; long j; float s;
  if (i < E1) {
    float t = *taup;
    float sp = (t > 20.f) ? t : log1pf(expf(t));
    s = (0.125f / (sp + 1e-6f)) * 1.44269504088896340736f;  // qkscale * log2(e)
    in = Wq; out = wqh; j = i;
  } else if (i < E2) {
    s = 1.f; in = Wkv; out = wkh; j = i - E1;
  } else {
    s = 1.f; in = Wp; out = wph; j = i - E2;
  }
  float4 f = *(const float4*)(in + j);
  *(uint2*)(out + j) = make_uint2(pk2(f.x * s, f.y * s), pk2(f.z * s, f.w * s));
}

// ---------------- NT GEMM: C[M,N] = A[M,K] @ B[N,K]^T, f16 MFMA, fp32 acc ---
// Tile 128(M) x BN(N), BK=64, K=768 (12 iters). 4 waves as 2x2 quadrants,
// each wave 64 x BN/2 (acc[4][BN/32]). 2-phase double-buffered staging.
// MODE 0: A is FP32 (x/y) -> fused convert: reg-stage A (2x float4/slab,
//   same chunk-XOR source permutation), pk2 -> ds_write_b128 to the identical
//   LDS layout. T14 split: loads issued before compute, ds_write after
//   (vmcnt latency hidden under MFMA). B (f16 weights) via global_load_lds.
//   This deletes the separate 150 MB cvt_xy round-trip.
//   by<6: A=x,B=Wq -> q [B,H,N,D] (scale pre-folded into Wq);
//   by>=6: A=y,B=Wkv -> cols[0,768) k [B,H,N,D]; [768,1536) v^T [B,H,D,N]
//   (v^T stored as 8B uint2: 4 consecutive n per lane)
// MODE 2: A=ao (f16, DMA-staged), B=Wproj -> fp32 out = acc + bias[n]
template<int MODE, int BN, int WPB>
__global__ __launch_bounds__(256, WPB) void gemm_k(
    const void* __restrict__ A0v, const void* __restrict__ A1v,
    const u16* __restrict__ B0, const u16* __restrict__ B1,
    u16* __restrict__ oq, u16* __restrict__ ok, u16* __restrict__ ovt,
    float* __restrict__ outf, const float* __restrict__ bias)
{
  constexpr int NT = BN / 32;                     // n-tiles per wave
  __shared__ __align__(16) u16 As[2][128 * 64];   // [buf][m][k] swizzled, 32 KB
  __shared__ __align__(16) u16 Bs[2][BN * 64];    // [buf][n][k] swizzled
  const int tid = threadIdx.x;
  const int wave = tid >> 6, lane = tid & 63;
  const int quad = lane >> 4, l16 = lane & 15;
  const int wr = wave >> 1, wc = wave & 1;        // wave quadrant (64m x BN/2)
  const int row0 = blockIdx.x * 128;
  const int by = blockIdx.y;

  const float* Af;            // MODE 0: fp32 A
  const u16* Ah;              // MODE 2: f16 A
  const u16* Bm; int cb;
  if (MODE == 0) {
    if (by < 6) { Af = (const float*)A0v; Bm = B0; cb = by; }
    else        { Af = (const float*)A1v; Bm = B1; cb = by - 6; }
    Ah = nullptr;
  } else {
    Ah = (const u16*)A0v; Bm = B0; cb = by; Af = nullptr;
  }
  const int col0 = cb * BN;

  const int sub = lane >> 3;                   // row within an 8-row DMA slab
  const int csw = ((lane & 7) ^ sub) * 8;      // swizzled source chunk (elems)

  f32x4 acc[4][NT] = {};
  f32x4 areg[4][2];                            // MODE 0: staged fp32 A (32 VGPR)

  auto stageA_load = [&](int k0) {             // MODE 0: issue global f32 loads
    #pragma unroll
    for (int i = 0; i < 4; i++) {
      int ii = wave * 4 + i;
      const float* p = Af + (size_t)(row0 + ii * 8 + sub) * 768 + k0 + csw;
      areg[i][0] = *(const f32x4*)p;
      areg[i][1] = *(const f32x4*)(p + 4);
    }
  };
  auto stageA_write = [&](int bsel) {          // MODE 0: cvt + LDS write
    #pragma unroll
    for (int i = 0; i < 4; i++) {
      int ii = wave * 4 + i;
      uint4 w = make_uint4(pk2(areg[i][0][0], areg[i][0][1]), pk2(areg[i][0][2], areg[i][0][3]),
                           pk2(areg[i][1][0], areg[i][1][1]), pk2(areg[i][1][2], areg[i][1][3]));
      *(uint4*)&As[bsel][ii * 512 + lane * 8] = w;
    }
  };
  auto stageA_dma = [&](int k0, int bsel) {    // MODE 2: f16 DMA
    #pragma unroll
    for (int i = 0; i < 4; i++) {
      int ii = wave * 4 + i;
      dma16(Ah + (size_t)(row0 + ii * 8 + sub) * 768 + k0 + csw, &As[bsel][ii * 512]);
    }
  };
  auto stageB = [&](int k0, int bsel) {
    #pragma unroll
    for (int i = 0; i < BN / 32; i++) {
      int ii = wave * (BN / 32) + i;           // B slabs 0..BN/8-1
      dma16(Bm + (size_t)(col0 + ii * 8 + sub) * 768 + k0 + csw, &Bs[bsel][ii * 512]);
    }
  };

  if (MODE == 0) { stageA_load(0); stageA_write(0); }
  else stageA_dma(0, 0);
  stageB(0, 0);
  __syncthreads();                             // tile-0 staged

  #pragma unroll 1
  for (int t = 0; t < 12; t++) {
    const int cur = t & 1;
    const bool pre = (t + 1 < 12);
    if (pre) {
      if (MODE == 0) stageA_load((t + 1) << 6);
      else stageA_dma((t + 1) << 6, cur ^ 1);
      stageB((t + 1) << 6, cur ^ 1);
    }
    const u16* Asp = As[cur];
    const u16* Bsp = Bs[cur];
    #pragma unroll
    for (int ks = 0; ks < 2; ks++) {
      half8 af[4], bfr[NT];
      #pragma unroll
      for (int mt = 0; mt < 4; mt++)
        af[mt] = *(const half8*)&Asp[(wr * 64 + mt * 16 + l16) * 64 + (((ks * 4 + quad) ^ (l16 & 7)) * 8)];
      #pragma unroll
      for (int nt = 0; nt < NT; nt++)
        bfr[nt] = *(const half8*)&Bsp[(wc * (BN / 2) + nt * 16 + l16) * 64 + (((ks * 4 + quad) ^ (l16 & 7)) * 8)];
      #pragma unroll
      for (int mt = 0; mt < 4; mt++)
        #pragma unroll
        for (int nt = 0; nt < NT; nt++)
          acc[mt][nt] = __builtin_amdgcn_mfma_f32_16x16x32_f16(af[mt], bfr[nt], acc[mt][nt], 0, 0, 0);
    }
    if (MODE == 0 && pre) stageA_write(cur ^ 1);   // vmcnt wait lands after MFMA
    __syncthreads();   // readers done with buf[cur]; prefetch DMA drained
  }

  // epilogue: C layout col=lane&15, row=quad*4+reg
  #pragma unroll
  for (int mt = 0; mt < 4; mt++)
  #pragma unroll
  for (int nt = 0; nt < NT; nt++) {
    int gm0 = row0 + wr * 64 + mt * 16 + quad * 4;
    int gn = col0 + wc * (BN / 2) + nt * 16 + l16;
    f32x4 v = acc[mt][nt];
    if (MODE == 0) {
      int b = gm0 >> 11, n0 = gm0 & 2047;
      if (by < 6) {
        int h = gn >> 6, d = gn & 63;
        size_t base = (((size_t)(b * NH + h)) * SEQ + n0) * 64 + d;
        #pragma unroll
        for (int r = 0; r < 4; r++) oq[base + (size_t)r * 64] = f2h(v[r]);
      } else if (gn < CDIM) {
        int h = gn >> 6, d = gn & 63;
        size_t base = (((size_t)(b * NH + h)) * SEQ + n0) * 64 + d;
        #pragma unroll
        for (int r = 0; r < 4; r++) ok[base + (size_t)r * 64] = f2h(v[r]);
      } else {
        int c = gn - CDIM;
        int h = c >> 6, d = c & 63;
        *(uint2*)&ovt[(((size_t)(b * NH + h)) * 64 + d) * SEQ + n0] =
            make_uint2(pk2(v[0], v[1]), pk2(v[2], v[3]));   // V^T: 4 consecutive n
      }
    } else {
      float bv = bias[gn];
      #pragma unroll
      for (int r = 0; r < 4; r++)
        outf[(size_t)(gm0 + r) * CDIM + gn] = v[r] + bv;
    }
  }
}

// ---------------- flash attention (transposed-S, f16, no-max softmax) ------
// QBLK=128, grid 768, chunked XCD swizzle (96 blocks = 6 heads/XCD -> 3 MB L2).
// NEW: T15-style software pipeline. V staged ONE TILE LATE (stageV(t) issued
// in iter t, consumed iter t+1), so PV(t-1) (MFMA, independent of sacc) sits
// in the same issue window as softmax(t) (VALU) -> matrix and vector pipes
// overlap instead of phase-lockstep (both were ~35% busy, mutually exclusive).
// Two named P-fragment sets pfX/pfY with compile-time parity (peel t=0,1 then
// unroll-by-2) -- no runtime-indexed arrays (scratch hazard).
// Hazards: stageV(t) overwrites V(t-2), whose readers (PV(t-2), iter t-1)
// finished before the iter t-1 barrier; DMA drained by each iter's barrier.
__global__ __launch_bounds__(256, 3) void attn_kernel(
    const u16* __restrict__ Q, const u16* __restrict__ Kb,
    const u16* __restrict__ Vtg, u16* __restrict__ Ob)
{
  __shared__ __align__(16) u16 Ks[2][64 * 64];    // [buf][kk][d] swizzled, 2x8 KB
  __shared__ __align__(16) u16 Vs[2][64 * 64];    // [buf][d][kk] swizzled, 2x8 KB
  __shared__ __align__(16) u16 Ps[4 * 16 * 64];   // per-wave 16x64 swizzled, 8 KB

  // bijective chunked XCD swizzle: 768 blocks = 8 XCDs x 96
  const int bid = (blockIdx.x & 7) * 96 + (blockIdx.x >> 3);
  const int qt = bid & 15;
  const int bh = bid >> 4;
  const int b = bh / NH, h = bh % NH;
  const u16* Qp = Q   + (size_t)bh * SEQ * 64;
  const u16* Kp = Kb  + (size_t)bh * SEQ * 64;
  const u16* Vp = Vtg + (size_t)bh * 64 * SEQ;

  const int tid = threadIdx.x;
  const int wave = tid >> 6, lane = tid & 63;
  const int quad = lane >> 4, l16 = lane & 15;
  const int sub = lane >> 3;
  const int csw = ((lane & 7) ^ sub) * 8;
  u16* Pw = Ps + wave * 16 * 64;

  half8 vone;
  #pragma unroll
  for (int j = 0; j < 8; j++) vone[j] = (_Float16)1.0f;

  // Q fragments (B-operand): Q[m=l16][d=ks*32+quad*8+j], scale pre-folded
  half8 qf[2][2];
  #pragma unroll
  for (int mt = 0; mt < 2; mt++)
    #pragma unroll
    for (int ks = 0; ks < 2; ks++)
      qf[mt][ks] = *(const half8*)(Qp + (size_t)(qt * 128 + wave * 32 + mt * 16 + l16) * 64 + ks * 32 + quad * 8);

  f32x4 oacc[2][4] = {};
  f32x4 lacc[2] = {};                          // row-sums via MFMA w/ ones
  half8 pfX[2][2], pfY[2][2];

  auto stageK = [&](int kt, int bsel) {
    #pragma unroll
    for (int i = 0; i < 2; i++) {
      int ii = wave * 2 + i;
      dma16(Kp + (size_t)(kt * 64 + ii * 8 + sub) * 64 + csw, &Ks[bsel][ii * 512]);
    }
  };
  auto stageV = [&](int kt, int bsel) {
    #pragma unroll
    for (int i = 0; i < 2; i++) {
      int ii = wave * 2 + i;
      dma16(Vp + (size_t)(ii * 8 + sub) * SEQ + kt * 64 + csw, &Vs[bsel][ii * 512]);
    }
  };

  // St = K Q^T : sacc[mt][ntk] holds St[kk=ntk*16+quad*4+r][m=l16]
  auto qk = [&](const u16* Ksp, f32x4 (&sacc)[2][4]) {
    __builtin_amdgcn_s_setprio(1);
    #pragma unroll
    for (int ks = 0; ks < 2; ks++) {
      #pragma unroll
      for (int ntk = 0; ntk < 4; ntk++) {
        half8 kf = *(const half8*)&Ksp[(ntk * 16 + l16) * 64 + (((ks * 4 + quad) ^ (l16 & 7)) * 8)];
        #pragma unroll
        for (int mt = 0; mt < 2; mt++)
          sacc[mt][ntk] = __builtin_amdgcn_mfma_f32_16x16x32_f16(kf, qf[mt][ks], sacc[mt][ntk], 0, 0, 0);
      }
    }
    __builtin_amdgcn_s_setprio(0);
  };
  // fixed-shift softmax p=exp2(s); P -> swizzled Ps (C->A layout) -> pcur
  auto softmax = [&](f32x4 (&sacc)[2][4], half8 (&pcur)[2][2]) {
    #pragma unroll
    for (int mt = 0; mt < 2; mt++) {
      #pragma unroll
      for (int ntk = 0; ntk < 4; ntk++) {
        float p0 = __builtin_amdgcn_exp2f(sacc[mt][ntk][0]);
        float p1 = __builtin_amdgcn_exp2f(sacc[mt][ntk][1]);
        float p2 = __builtin_amdgcn_exp2f(sacc[mt][ntk][2]);
        float p3 = __builtin_amdgcn_exp2f(sacc[mt][ntk][3]);
        *(uint2*)&Pw[l16 * 64 + (((ntk * 2 + (quad >> 1)) ^ (l16 & 7)) * 8) + (quad & 1) * 4] =
            make_uint2(pk2(p0, p1), pk2(p2, p3));
      }
      pcur[mt][0] = *(const half8*)&Pw[l16 * 64 + ((quad ^ (l16 & 7)) * 8)];
      pcur[mt][1] = *(const half8*)&Pw[l16 * 64 + (((4 + quad) ^ (l16 & 7)) * 8)];
    }
  };
  auto pv = [&](const u16* Vsp, half8 (&pprev)[2][2]) {
    #pragma unroll
    for (int ks = 0; ks < 2; ks++)
      #pragma unroll
      for (int dt = 0; dt < 4; dt++) {
        half8 vf = *(const half8*)&Vsp[(dt * 16 + l16) * 64 + (((ks * 4 + quad) ^ (l16 & 7)) * 8)];
        #pragma unroll
        for (int mt = 0; mt < 2; mt++)
          oacc[mt][dt] = __builtin_amdgcn_mfma_f32_16x16x32_f16(pprev[mt][ks], vf, oacc[mt][dt], 0, 0, 0);
      }
  };
  auto lsum = [&](half8 (&pcur)[2][2]) {
    #pragma unroll
    for (int ks = 0; ks < 2; ks++)
      #pragma unroll
      for (int mt = 0; mt < 2; mt++)
        lacc[mt] = __builtin_amdgcn_mfma_f32_16x16x32_f16(pcur[mt][ks], vone, lacc[mt], 0, 0, 0);
  };

  stageK(0, 0);
  __syncthreads();                             // K0 ready

  { // t = 0: no PV yet
    f32x4 sacc[2][4] = {};
    qk(Ks[0], sacc);
    stageK(1, 1); stageV(0, 0);
    softmax(sacc, pfX);
    __builtin_amdgcn_s_setprio(1); lsum(pfX); __builtin_amdgcn_s_setprio(0);
    __syncthreads();
  }
  { // t = 1
    f32x4 sacc[2][4] = {};
    qk(Ks[1], sacc);
    stageK(2, 0); stageV(1, 1);
    __builtin_amdgcn_s_setprio(1); pv(Vs[0], pfX); __builtin_amdgcn_s_setprio(0);
    softmax(sacc, pfY);
    __builtin_amdgcn_s_setprio(1); lsum(pfY); __builtin_amdgcn_s_setprio(0);
    __syncthreads();
  }
  #pragma unroll 1
  for (int u = 1; u < 16; ++u) {
    const int t0 = 2 * u;
    { // even tile: cur->pfX, prev=pfY, K in Ks[0], V(prev) in Vs[1]
      f32x4 sacc[2][4] = {};
      qk(Ks[0], sacc);
      stageK(t0 + 1, 1); stageV(t0, 0);
      __builtin_amdgcn_s_setprio(1); pv(Vs[1], pfY); __builtin_amdgcn_s_setprio(0);
      softmax(sacc, pfX);
      __builtin_amdgcn_s_setprio(1); lsum(pfX); __builtin_amdgcn_s_setprio(0);
      __syncthreads();
    }
    { // odd tile: cur->pfY, prev=pfX, K in Ks[1], V(prev) in Vs[0]
      f32x4 sacc[2][4] = {};
      qk(Ks[1], sacc);
      if (t0 + 2 < 32) stageK(t0 + 2, 0);
      stageV(t0 + 1, 1);
      __builtin_amdgcn_s_setprio(1); pv(Vs[0], pfX); __builtin_amdgcn_s_setprio(0);
      softmax(sacc, pfY);
      __builtin_amdgcn_s_setprio(1); lsum(pfY); __builtin_amdgcn_s_setprio(0);
      __syncthreads();
    }
  }
  // drain: PV(31) (V(31) staged iter 31, drained at its barrier)
  pv(Vs[1], pfY);

  // epilogue: O / l -> ao[b][n][h*64+d] (f16); lacc row layout == oacc rows
  #pragma unroll
  for (int mt = 0; mt < 2; mt++) {
    #pragma unroll
    for (int r = 0; r < 4; r++) {
      float inv = 1.0f / lacc[mt][r];
      int n = qt * 128 + wave * 32 + mt * 16 + quad * 4 + r;
      size_t base = ((size_t)b * SEQ + n) * CDIM + h * 64;
      #pragma unroll
      for (int dt = 0; dt < 4; dt++)
        Ob[base + dt * 16 + l16] = f2h(oacc[mt][dt][r] * inv);
    }
  }
}

// ---------------- launch ----------------
extern "C" void kernel_launch(void* const* d_in, const int* in_sizes, int n_in,
                              void* d_out, int out_size, void* d_ws, size_t ws_size,
                              hipStream_t stream)
{
  const float* x     = (const float*)d_in[0];
  const float* y     = (const float*)d_in[1];
  const float* Wq    = (const float*)d_in[2];
  const float* Wkv   = (const float*)d_in[3];
  const float* taup  = (const float*)d_in[4];
  const float* Wproj = (const float*)d_in[5];
  const float* bproj = (const float*)d_in[6];
  float* out = (float*)d_out;

  char* ws = (char*)d_ws;
  size_t off = 0;
  auto alloc = [&](size_t bytes) { char* p = ws + off; off += bytes; return p; };
  u16* wqh = (u16*)alloc(768ull * 768 * 2);
  u16* wkh = (u16*)alloc(1536ull * 768 * 2);
  u16* wph = (u16*)alloc(768ull * 768 * 2);
  u16* qb  = (u16*)alloc(8192ull * 768 * 2);   // [B,H,N,D] f16, scale folded
  u16* kb  = (u16*)alloc(8192ull * 768 * 2);   // [B,H,N,D]
  u16* vtb = (u16*)alloc(8192ull * 768 * 2);   // [B,H,D,N]
  u16* ao  = (u16*)alloc(8192ull * 768 * 2);   // [B,N,C]

  cvt_w<<<2304, 256, 0, stream>>>(Wq, Wkv, Wproj, taup, wqh, wkh, wph);

  // fused QKV GEMM, fp32 A with in-kernel convert: by<6 -> Q, by in [6,18) -> KV
  gemm_k<0, 128, 2><<<dim3(64, 18), 256, 0, stream>>>(x, y, wqh, wkh, qb, kb, vtb, nullptr, nullptr);
  attn_kernel<<<dim3(768), 256, 0, stream>>>(qb, kb, vtb, ao);
  gemm_k<2, 64, 3><<<dim3(64, 12), 256, 0, stream>>>(ao, nullptr, wph, nullptr, nullptr, nullptr, nullptr, out, bproj);
}